// Round 1
// baseline (9442.639 us; speedup 1.0000x reference)
//
#include <hip/hip_runtime.h>
#include <cmath>

// LocalRNN: B=32, L=2048, D=512, KSIZE=3, GRU gates r,z,n.
// Step t (t=0,1,2):
//   gi = x[:, l-(2-t)] @ W_ih^T + b_ih   (zero row if l-(2-t) < 0)
//   gh = h @ W_hh^T + b_hh               (h == 0 for t=0)
//   r = sigmoid(gi_r + gh_r); z = sigmoid(gi_z + gh_z)
//   n = tanh(gi_n + r * gh_n)
//   h' = (1-z)*n + z*h
// Each step = one GEMM-with-epilogue kernel. Ping-pong: out -> ws -> out.

#define DDIM 512
#define LSEQ 2048
#define BATCH 32
#define MT 64          // rows (b,l positions) per block
#define DT 64          // d-columns per block
#define KT 16          // K chunk
#define MP (MT + 4)    // LDS pad: stride 68 floats = 272B, 16B-aligned

__device__ __forceinline__ float sigmoid_f(float s) {
    // exp overflow -> inf -> 1/(1+inf) = 0 : safe
    return 1.0f / (1.0f + __expf(-s));
}
__device__ __forceinline__ float tanh_f(float a) {
    a = fminf(fmaxf(a, -15.0f), 15.0f);
    float e = __expf(-2.0f * a);
    return (1.0f - e) / (1.0f + e);
}

template <int T>
__global__ __launch_bounds__(256) void lrnn_step(
    const float* __restrict__ x, const float* __restrict__ Wih,
    const float* __restrict__ Whh, const float* __restrict__ bih,
    const float* __restrict__ bhh, const float* __restrict__ hin,
    float* __restrict__ hout)
{
    __shared__ float sAx[KT][MP];        // x tile, transposed [k][m]
    __shared__ float sAh[KT][MP];        // h tile
    __shared__ float sWi[3][KT][MP];     // W_ih rows {d0..}[+512][+1024], [k][d]
    __shared__ float sWh[3][KT][MP];

    const int tid = threadIdx.x;
    const int d0 = blockIdx.x * DT;
    const int m0 = blockIdx.y * MT;

    const int ty = tid >> 4;   // 0..15
    const int tx = tid & 15;   // 0..15
    const int mm0 = ty * 4;
    const int dd0 = tx * 4;

    float accI[3][4][4] = {};  // gi accumulators (r,z,n)
    float accH[3][4][4] = {};  // gh accumulators

    for (int k0 = 0; k0 < DDIM; k0 += KT) {
        // ---- stage A tiles (coalesced along k, transposed into LDS) ----
        #pragma unroll
        for (int i = 0; i < 4; ++i) {
            int e  = i * 256 + tid;
            int kk = e & (KT - 1);
            int mm = e >> 4;               // KT==16
            int m  = m0 + mm;
            int l  = m & (LSEQ - 1);
            int b  = m >> 11;              // L==2048
            int lx = l - (2 - T);
            float vx = 0.0f;
            if (lx >= 0) vx = x[(b * LSEQ + lx) * DDIM + k0 + kk];
            sAx[kk][mm] = vx;
            if (T > 0) sAh[kk][mm] = hin[m * DDIM + k0 + kk];
        }
        // ---- stage W tiles ----
        #pragma unroll
        for (int g = 0; g < 3; ++g) {
            #pragma unroll
            for (int i = 0; i < 4; ++i) {
                int e  = i * 256 + tid;
                int kk = e & (KT - 1);
                int dd = e >> 4;
                int idx = (g * DDIM + d0 + dd) * DDIM + k0 + kk;
                sWi[g][kk][dd] = Wih[idx];
                if (T > 0) sWh[g][kk][dd] = Whh[idx];
            }
        }
        __syncthreads();

        // ---- compute: 4x4 register tile, 6 accs per output ----
        #pragma unroll
        for (int kk = 0; kk < KT; ++kk) {
            float ax[4], ah[4];
            #pragma unroll
            for (int i = 0; i < 4; ++i) ax[i] = sAx[kk][mm0 + i];
            if (T > 0) {
                #pragma unroll
                for (int i = 0; i < 4; ++i) ah[i] = sAh[kk][mm0 + i];
            }
            #pragma unroll
            for (int g = 0; g < 3; ++g) {
                float wi[4], wh[4];
                #pragma unroll
                for (int j = 0; j < 4; ++j) wi[j] = sWi[g][kk][dd0 + j];
                if (T > 0) {
                    #pragma unroll
                    for (int j = 0; j < 4; ++j) wh[j] = sWh[g][kk][dd0 + j];
                }
                #pragma unroll
                for (int i = 0; i < 4; ++i)
                    #pragma unroll
                    for (int j = 0; j < 4; ++j) {
                        accI[g][i][j] += ax[i] * wi[j];
                        if (T > 0) accH[g][i][j] += ah[i] * wh[j];
                    }
            }
        }
        __syncthreads();
    }

    // ---- epilogue: gates + h update ----
    #pragma unroll
    for (int j = 0; j < 4; ++j) {
        int d = d0 + dd0 + j;
        float bir = bih[d],            bhr = bhh[d];
        float biz = bih[d + DDIM],     bhz = bhh[d + DDIM];
        float bin = bih[d + 2 * DDIM], bhn = bhh[d + 2 * DDIM];
        #pragma unroll
        for (int i = 0; i < 4; ++i) {
            int m = m0 + mm0 + i;
            float gir = accI[0][i][j] + bir;
            float ghr = accH[0][i][j] + bhr;
            float giz = accI[1][i][j] + biz;
            float ghz = accH[1][i][j] + bhz;
            float gin = accI[2][i][j] + bin;
            float ghn = accH[2][i][j] + bhn;
            float r = sigmoid_f(gir + ghr);
            float z = sigmoid_f(giz + ghz);
            float n = tanh_f(gin + r * ghn);
            float hp = (T == 0) ? 0.0f : hin[m * DDIM + d];
            hout[m * DDIM + d] = (1.0f - z) * n + z * hp;
        }
    }
}

extern "C" void kernel_launch(void* const* d_in, const int* in_sizes, int n_in,
                              void* d_out, int out_size, void* d_ws, size_t ws_size,
                              hipStream_t stream) {
    const float* x   = (const float*)d_in[0];
    const float* Wih = (const float*)d_in[1];
    const float* Whh = (const float*)d_in[2];
    const float* bih = (const float*)d_in[3];
    const float* bhh = (const float*)d_in[4];
    float* out  = (float*)d_out;
    float* hbuf = (float*)d_ws;   // needs B*L*D*4 = 134 MB

    dim3 grid(DDIM / DT, (BATCH * LSEQ) / MT);  // (8, 1024)
    dim3 block(256);
    // t=0: h==0, write h1 -> d_out
    lrnn_step<0><<<grid, block, 0, stream>>>(x, Wih, Whh, bih, bhh, nullptr, out);
    // t=1: read d_out, write h2 -> ws
    lrnn_step<1><<<grid, block, 0, stream>>>(x, Wih, Whh, bih, bhh, out, hbuf);
    // t=2: read ws, write final -> d_out
    lrnn_step<2><<<grid, block, 0, stream>>>(x, Wih, Whh, bih, bhh, hbuf, out);
}

// Round 3
// 1568.733 us; speedup vs baseline: 6.0193x; 6.0193x over previous
//
#include <hip/hip_runtime.h>
#include <hip/hip_bf16.h>

// LocalRNN via bf16 MFMA: B=32, L=2048, D=512, KSIZE=3, gates r,z,n.
// Step t: gi = x[:,l-(2-t)] @ Wih^T, gh = h @ Whh^T (bf16 MFMA, f32 accum),
// epilogue gates in f32. Ping-pong: d_out -> ws -> d_out (no in-place step:
// blocks read ALL columns of their h rows, other d-blocks write them).

#define DDIM 512
#define LSEQ 2048
#define BATCH 32
#define MROWS (BATCH * LSEQ)   // 65536
#define MT 128                 // rows per block
#define DTG 32                 // gate columns per block (n-width = 6*DTG over 6 matrices)
#define KC 32                  // K chunk

typedef short bf16x8 __attribute__((ext_vector_type(8)));
typedef float f32x4 __attribute__((ext_vector_type(4)));

__device__ __forceinline__ float sigmoid_f(float s) { return 1.0f / (1.0f + __expf(-s)); }
__device__ __forceinline__ float tanh_f(float a) {
    a = fminf(fmaxf(a, -15.0f), 15.0f);
    float e = __expf(-2.0f * a);
    return (1.0f - e) / (1.0f + e);
}
__device__ __forceinline__ ushort f2bf(float f) {
    union { __hip_bfloat16 b; ushort u; } cv;
    cv.b = __float2bfloat16(f);
    return cv.u;
}

// Waves: wid 0..3 -> (wm = wid>>1: m-half 64 rows, wd = wid&1: d-half 16 cols).
// Per wave: mf=4 m-frags (16x16), 1 n-frag per matrix, 6 matrices -> acc[6][4] f32x4.
template <int T>
__global__ __launch_bounds__(256, 2) void lrnn_step(
    const float* __restrict__ x, const float* __restrict__ Wih,
    const float* __restrict__ Whh, const float* __restrict__ bih,
    const float* __restrict__ bhh, const float* __restrict__ hin,
    float* __restrict__ hout)
{
    __shared__ ushort sX[MT * KC];          // [128][32] bf16, 8KB
    __shared__ ushort sWi[3 * DTG * KC];    // [96][32], 6KB
    __shared__ ushort sH[MT * KC];          // 8KB (unused T=0)
    __shared__ ushort sWh[3 * DTG * KC];    // 6KB (unused T=0)

    const int tid  = threadIdx.x;
    const int wid  = tid >> 6;
    const int lane = tid & 63;
    const int wm = wid >> 1;        // 0..1
    const int wd = wid & 1;         // 0..1
    const int lrow = lane & 15;
    const int lk   = lane >> 4;     // 0..3
    const int d0 = blockIdx.x * DTG;
    const int m0 = blockIdx.y * MT;
    const int l0 = m0 & (LSEQ - 1); // tiles never cross batch boundary (2048%128==0)

    const int dcol = d0 + wd * 16 + lrow;
    const float bir = bih[dcol], biz = bih[dcol + DDIM], bin = bih[dcol + 2 * DDIM];
    const float bhr = bhh[dcol], bhz = bhh[dcol + DDIM], bhn = bhh[dcol + 2 * DDIM];

    f32x4 accI[3][4] = {};
    f32x4 accH[3][4] = {};

    for (int k0 = 0; k0 < DDIM; k0 += KC) {
        // ---- stage X (shifted, zero-pad l<0) and H: 1024 float4 segs each ----
        #pragma unroll
        for (int p = 0; p < 4; ++p) {
            int seg = tid + p * 256;
            int row = seg >> 3;
            int kf  = (seg & 7) * 4;
            int lxr = l0 + row - (2 - T);
            ushort4 o = {0, 0, 0, 0};
            if (lxr >= 0) {
                float4 v = *(const float4*)&x[(size_t)(m0 + row - (2 - T)) * DDIM + k0 + kf];
                o.x = f2bf(v.x); o.y = f2bf(v.y); o.z = f2bf(v.z); o.w = f2bf(v.w);
            }
            *(ushort4*)&sX[row * KC + kf] = o;
            if constexpr (T > 0) {
                float4 h4 = *(const float4*)&hin[(size_t)(m0 + row) * DDIM + k0 + kf];
                ushort4 oh = { f2bf(h4.x), f2bf(h4.y), f2bf(h4.z), f2bf(h4.w) };
                *(ushort4*)&sH[row * KC + kf] = oh;
            }
        }
        // ---- stage Wi / Wh: 96 rows x 32 k = 768 float4 segs each ----
        #pragma unroll
        for (int p = 0; p < 3; ++p) {
            int seg = tid + p * 256;
            int row = seg >> 3;            // 0..95 = g*32 + dd
            int kf  = (seg & 7) * 4;
            int g = row >> 5, dd = row & 31;
            size_t widx = (size_t)(g * DDIM + d0 + dd) * DDIM + k0 + kf;
            float4 v = *(const float4*)&Wih[widx];
            ushort4 o = { f2bf(v.x), f2bf(v.y), f2bf(v.z), f2bf(v.w) };
            *(ushort4*)&sWi[row * KC + kf] = o;
            if constexpr (T > 0) {
                float4 w = *(const float4*)&Whh[widx];
                ushort4 oh = { f2bf(w.x), f2bf(w.y), f2bf(w.z), f2bf(w.w) };
                *(ushort4*)&sWh[row * KC + kf] = oh;
            }
        }
        __syncthreads();

        // ---- fragments + MFMA ----
        bf16x8 ax[4], ah[4];
        #pragma unroll
        for (int mi = 0; mi < 4; ++mi)
            ax[mi] = *(const bf16x8*)&sX[(wm * 64 + mi * 16 + lrow) * KC + lk * 8];
        if constexpr (T > 0) {
            #pragma unroll
            for (int mi = 0; mi < 4; ++mi)
                ah[mi] = *(const bf16x8*)&sH[(wm * 64 + mi * 16 + lrow) * KC + lk * 8];
        }
        #pragma unroll
        for (int g = 0; g < 3; ++g) {
            bf16x8 bi = *(const bf16x8*)&sWi[(g * DTG + wd * 16 + lrow) * KC + lk * 8];
            #pragma unroll
            for (int mi = 0; mi < 4; ++mi)
                accI[g][mi] = __builtin_amdgcn_mfma_f32_16x16x32_bf16(ax[mi], bi, accI[g][mi], 0, 0, 0);
            if constexpr (T > 0) {
                bf16x8 bh = *(const bf16x8*)&sWh[(g * DTG + wd * 16 + lrow) * KC + lk * 8];
                #pragma unroll
                for (int mi = 0; mi < 4; ++mi)
                    accH[g][mi] = __builtin_amdgcn_mfma_f32_16x16x32_bf16(ah[mi], bh, accH[g][mi], 0, 0, 0);
            }
        }
        __syncthreads();
    }

    // ---- epilogue: C/D frag (col=lane&15, row=lk*4+j) -> gates -> h' ----
    #pragma unroll
    for (int mi = 0; mi < 4; ++mi) {
        #pragma unroll
        for (int j = 0; j < 4; ++j) {
            int m = m0 + wm * 64 + mi * 16 + lk * 4 + j;
            size_t off = (size_t)m * DDIM + dcol;
            float gir = accI[0][mi][j] + bir;
            float giz = accI[1][mi][j] + biz;
            float gin = accI[2][mi][j] + bin;
            float ghr = bhr, ghz = bhz, ghn = bhn, hp = 0.0f;
            if constexpr (T > 0) {
                ghr += accH[0][mi][j];
                ghz += accH[1][mi][j];
                ghn += accH[2][mi][j];
                hp = hin[off];
            }
            float r = sigmoid_f(gir + ghr);
            float z = sigmoid_f(giz + ghz);
            float n = tanh_f(gin + r * ghn);
            hout[off] = (1.0f - z) * n + z * hp;
        }
    }
}

extern "C" void kernel_launch(void* const* d_in, const int* in_sizes, int n_in,
                              void* d_out, int out_size, void* d_ws, size_t ws_size,
                              hipStream_t stream) {
    const float* x   = (const float*)d_in[0];
    const float* Wih = (const float*)d_in[1];
    const float* Whh = (const float*)d_in[2];
    const float* bih = (const float*)d_in[3];
    const float* bhh = (const float*)d_in[4];
    float* out  = (float*)d_out;
    float* hbuf = (float*)d_ws;   // 134 MB f32 ping (known-safe from round 0)

    dim3 grid(DDIM / DTG, MROWS / MT);   // (16, 512)
    dim3 block(256);
    lrnn_step<0><<<grid, block, 0, stream>>>(x, Wih, Whh, bih, bhh, nullptr, out);
    lrnn_step<1><<<grid, block, 0, stream>>>(x, Wih, Whh, bih, bhh, out, hbuf);
    lrnn_step<2><<<grid, block, 0, stream>>>(x, Wih, Whh, bih, bhh, hbuf, out);
}

// Round 4
// 1400.195 us; speedup vs baseline: 6.7438x; 1.1204x over previous
//
#include <hip/hip_runtime.h>
#include <hip/hip_bf16.h>
#include <stdint.h>

// LocalRNN, bf16-everything MFMA version.
// Pre-pass converts W (and x, if ws allows) to bf16; h ping-pongs as bf16 in ws.
// Step kernels stage via global_load_lds(16B) into linear LDS whose CONTENT is
// XOR-swizzled (slot ^= row&7, 128B rows) by pre-swizzling the global source
// (G21: both-sides-or-neither). Fragment reads are then ~2-way bank conflicts.

#define DDIM 512
#define LSEQ 2048
#define BATCH 32
#define MROWS (BATCH * LSEQ)   // 65536
#define MT 128                 // rows / block
#define DTG 32                 // d-cols / block
#define KC 64                  // bf16 K-chunk -> 128 B LDS rows

typedef short  bf16x8   __attribute__((ext_vector_type(8)));
typedef float  f32x4    __attribute__((ext_vector_type(4)));
typedef ushort ushort8_t __attribute__((ext_vector_type(8)));

__device__ __forceinline__ float sigmoid_f(float s) { return 1.0f / (1.0f + __expf(-s)); }
__device__ __forceinline__ float tanh_f(float a) {
    a = fminf(fmaxf(a, -15.0f), 15.0f);
    float e = __expf(-2.0f * a);
    return (1.0f - e) / (1.0f + e);
}
__device__ __forceinline__ ushort f2bf(float f) {
    union { __hip_bfloat16 b; ushort u; } cv; cv.b = __float2bfloat16(f); return cv.u;
}
__device__ __forceinline__ float bf2f(ushort u) {
    union { float f; uint32_t v; } cv; cv.v = ((uint32_t)u) << 16; return cv.f;
}
__device__ __forceinline__ ushort8_t pack8(float4 a, float4 b) {
    ushort8_t o = { f2bf(a.x), f2bf(a.y), f2bf(a.z), f2bf(a.w),
                    f2bf(b.x), f2bf(b.y), f2bf(b.z), f2bf(b.w) };
    return o;
}

#define GLD_LDS16(gsrc, ldst) \
    __builtin_amdgcn_global_load_lds((const __attribute__((address_space(1))) void*)(gsrc), \
                                     (__attribute__((address_space(3))) void*)(ldst), 16, 0, 0)

// ---------------- pre-pass: f32 -> bf16 ----------------
__global__ __launch_bounds__(256) void conv_w(const float* __restrict__ a, const float* __restrict__ b,
                                              ushort* __restrict__ oa, ushort* __restrict__ ob) {
    size_t e = ((size_t)blockIdx.x * 256 + threadIdx.x) * 8;   // 98304 threads x 8 elems
    float4 p = *(const float4*)&a[e], q = *(const float4*)&a[e + 4];
    *(ushort8_t*)&oa[e] = pack8(p, q);
    p = *(const float4*)&b[e]; q = *(const float4*)&b[e + 4];
    *(ushort8_t*)&ob[e] = pack8(p, q);
}

__global__ __launch_bounds__(256) void conv_x(const float* __restrict__ x, ushort* __restrict__ xb) {
    const size_t total = (size_t)MROWS * DDIM / 8;
    for (size_t u = (size_t)blockIdx.x * 256 + threadIdx.x; u < total; u += (size_t)gridDim.x * 256) {
        size_t e = u * 8;
        float4 p = *(const float4*)&x[e], q = *(const float4*)&x[e + 4];
        *(ushort8_t*)&xb[e] = pack8(p, q);
    }
}

// ---------------- step kernel ----------------
// Waves: wm = wid>>1 (64 rows), wd = wid&1 (16 cols). acc[6][4] f32x4 (96 VGPR).
// XB: x pre-converted (global_load_lds); else f32 load+cvt.
// WB: W pre-converted (global_load_lds); else f32 load+cvt.
template <int T, int XB, int WB>
__global__ __launch_bounds__(256) void lrnn_step(
    const float* __restrict__ xf, const ushort* __restrict__ xb,
    const float* __restrict__ Wif, const float* __restrict__ Whf,
    const ushort* __restrict__ Wib, const ushort* __restrict__ Whb,
    const float* __restrict__ bih, const float* __restrict__ bhh,
    const ushort* __restrict__ hin, ushort* __restrict__ hout_b,
    float* __restrict__ hout_f)
{
    __shared__ ushort sX[MT * KC];                       // 16 KB
    __shared__ ushort sWi[96 * KC];                      // 12 KB
    __shared__ ushort sH[(T > 0) ? (MT * KC) : 8];       // 16 KB (T>0)
    __shared__ ushort sWh[(T > 0) ? (96 * KC) : 8];      // 12 KB (T>0)

    const int tid = threadIdx.x;
    const int wid = tid >> 6, lane = tid & 63;
    const int wm = wid >> 1, wd = wid & 1;
    const int lrow = lane & 15, lk = lane >> 4;
    const int d0 = blockIdx.x * DTG;
    const int m0 = blockIdx.y * MT;
    const int l0 = m0 & (LSEQ - 1);
    const int dcol = d0 + wd * 16 + lrow;

    // bias folded into accumulator init (C-in of first MFMA)
    f32x4 accI[3][4], accH[3][4];
    #pragma unroll
    for (int g = 0; g < 3; ++g) {
        float bi = bih[g * DDIM + dcol];
        if (T == 0 && g < 2) bi += bhh[g * DDIM + dcol];
        float bh = (T > 0) ? bhh[g * DDIM + dcol] : 0.0f;
        #pragma unroll
        for (int mi = 0; mi < 4; ++mi) {
            accI[g][mi] = { bi, bi, bi, bi };
            accH[g][mi] = { bh, bh, bh, bh };
        }
    }
    const float bhn0 = (T == 0) ? bhh[2 * DDIM + dcol] : 0.0f;

    for (int k0 = 0; k0 < DDIM; k0 += KC) {
        // ---- stage X (shift 2-T, clamp+zero), H ----
        #pragma unroll
        for (int c = 0; c < 4; ++c) {
            int seg = c * 256 + tid;
            int row = seg >> 3, slot = seg & 7;
            int msrc = m0 + row - (2 - T);
            if (T < 2 && msrc < 0) msrc = 0;
            int koff = k0 + ((slot ^ (row & 7)) << 3);   // pre-swizzled source slot
            if constexpr (XB) {
                GLD_LDS16(xb + (size_t)msrc * DDIM + koff, &sX[seg * 8]);
            } else {
                const float* s = xf + (size_t)msrc * DDIM + koff;
                float4 a = *(const float4*)s, b = *(const float4*)(s + 4);
                *(ushort8_t*)&sX[seg * 8] = pack8(a, b);
            }
            if constexpr (T > 0) {
                GLD_LDS16(hin + (size_t)(m0 + row) * DDIM + koff, &sH[seg * 8]);
            }
        }
        // ---- stage Wi / Wh tiles [96][KC] ----
        #pragma unroll
        for (int c = 0; c < 3; ++c) {
            int seg = c * 256 + tid;
            int row = seg >> 3, slot = seg & 7;
            int g = row >> 5, dd = row & 31;
            int koff = k0 + ((slot ^ (row & 7)) << 3);
            size_t gw = (size_t)(g * DDIM + d0 + dd) * DDIM + koff;
            if constexpr (WB) {
                GLD_LDS16(Wib + gw, &sWi[seg * 8]);
                if constexpr (T > 0) GLD_LDS16(Whb + gw, &sWh[seg * 8]);
            } else {
                {
                    const float* s = Wif + gw;
                    float4 a = *(const float4*)s, b = *(const float4*)(s + 4);
                    *(ushort8_t*)&sWi[seg * 8] = pack8(a, b);
                }
                if constexpr (T > 0) {
                    const float* s = Whf + gw;
                    float4 a = *(const float4*)s, b = *(const float4*)(s + 4);
                    *(ushort8_t*)&sWh[seg * 8] = pack8(a, b);
                }
            }
        }
        __syncthreads();
        // zero left-pad rows (only batch-start blocks, T<2)
        if constexpr (T < 2) {
            if (l0 == 0) {
                if (tid < (2 - T) * 8) {
                    ushort8_t z = { 0, 0, 0, 0, 0, 0, 0, 0 };
                    *(ushort8_t*)&sX[tid * 8] = z;
                }
                __syncthreads();
            }
        }
        // ---- compute: 2 ksteps of 16x16x32 ----
        #pragma unroll
        for (int kk = 0; kk < 2; ++kk) {
            bf16x8 ax[4], ah[4];
            #pragma unroll
            for (int mi = 0; mi < 4; ++mi) {
                int r = wm * 64 + mi * 16 + lrow;
                int sl = (kk * 4 + lk) ^ (r & 7);
                ax[mi] = *(const bf16x8*)&sX[r * KC + sl * 8];
                if constexpr (T > 0) ah[mi] = *(const bf16x8*)&sH[r * KC + sl * 8];
            }
            #pragma unroll
            for (int g = 0; g < 3; ++g) {
                int rw = g * 32 + wd * 16 + lrow;
                int sl = (kk * 4 + lk) ^ (rw & 7);
                bf16x8 bi = *(const bf16x8*)&sWi[rw * KC + sl * 8];
                #pragma unroll
                for (int mi = 0; mi < 4; ++mi)
                    accI[g][mi] = __builtin_amdgcn_mfma_f32_16x16x32_bf16(ax[mi], bi, accI[g][mi], 0, 0, 0);
                if constexpr (T > 0) {
                    bf16x8 bh = *(const bf16x8*)&sWh[rw * KC + sl * 8];
                    #pragma unroll
                    for (int mi = 0; mi < 4; ++mi)
                        accH[g][mi] = __builtin_amdgcn_mfma_f32_16x16x32_bf16(ah[mi], bh, accH[g][mi], 0, 0, 0);
                }
            }
        }
        __syncthreads();
    }

    // ---- epilogue: gates (C/D: col=lane&15, row=lk*4+j) ----
    #pragma unroll
    for (int mi = 0; mi < 4; ++mi) {
        #pragma unroll
        for (int j = 0; j < 4; ++j) {
            int m = m0 + wm * 64 + mi * 16 + lk * 4 + j;
            size_t off = (size_t)m * DDIM + dcol;
            float h;
            if constexpr (T == 0) {
                float r = sigmoid_f(accI[0][mi][j]);
                float z = sigmoid_f(accI[1][mi][j]);
                float n = tanh_f(accI[2][mi][j] + r * bhn0);
                h = (1.0f - z) * n;
            } else {
                float r = sigmoid_f(accI[0][mi][j] + accH[0][mi][j]);
                float z = sigmoid_f(accI[1][mi][j] + accH[1][mi][j]);
                float n = tanh_f(accI[2][mi][j] + r * accH[2][mi][j]);
                float hp = bf2f(hin[off]);
                h = (1.0f - z) * n + z * hp;
            }
            if constexpr (T == 2) hout_f[off] = h;
            else                  hout_b[off] = f2bf(h);
        }
    }
}

extern "C" void kernel_launch(void* const* d_in, const int* in_sizes, int n_in,
                              void* d_out, int out_size, void* d_ws, size_t ws_size,
                              hipStream_t stream) {
    const float* x   = (const float*)d_in[0];
    const float* Wih = (const float*)d_in[1];
    const float* Whh = (const float*)d_in[2];
    const float* bih = (const float*)d_in[3];
    const float* bhh = (const float*)d_in[4];
    float* out = (float*)d_out;

    const size_t HELEMS = (size_t)MROWS * DDIM;    // 33,554,432
    const size_t WELEMS = (size_t)3 * DDIM * DDIM; // 786,432
    ushort* hA  = (ushort*)d_ws;
    ushort* hB  = hA + HELEMS;
    ushort* Wib = hB + HELEMS;
    ushort* Whb = Wib + WELEMS;
    ushort* xbp = Whb + WELEMS;
    const size_t NEED_W = (2 * HELEMS + 2 * WELEMS) * 2;  // 137,363,456 B
    const size_t NEED_X = NEED_W + HELEMS * 2;            // 204,472,320 B
    const bool wb  = ws_size >= NEED_W;
    const bool xbv = ws_size >= NEED_X;

    dim3 grid(DDIM / DTG, MROWS / MT);   // (16, 512)
    if (wb)  conv_w<<<(int)(WELEMS / 8 / 256), 256, 0, stream>>>(Wih, Whh, Wib, Whb);
    if (xbv) conv_x<<<2048, 256, 0, stream>>>(x, xbp);

    if (xbv) {
        lrnn_step<0,1,1><<<grid,256,0,stream>>>(x, xbp, Wih, Whh, Wib, Whb, bih, bhh, nullptr, hA, nullptr);
        lrnn_step<1,1,1><<<grid,256,0,stream>>>(x, xbp, Wih, Whh, Wib, Whb, bih, bhh, hA, hB, nullptr);
        lrnn_step<2,1,1><<<grid,256,0,stream>>>(x, xbp, Wih, Whh, Wib, Whb, bih, bhh, hB, nullptr, out);
    } else if (wb) {
        lrnn_step<0,0,1><<<grid,256,0,stream>>>(x, xbp, Wih, Whh, Wib, Whb, bih, bhh, nullptr, hA, nullptr);
        lrnn_step<1,0,1><<<grid,256,0,stream>>>(x, xbp, Wih, Whh, Wib, Whb, bih, bhh, hA, hB, nullptr);
        lrnn_step<2,0,1><<<grid,256,0,stream>>>(x, xbp, Wih, Whh, Wib, Whb, bih, bhh, hB, nullptr, out);
    } else {
        lrnn_step<0,0,0><<<grid,256,0,stream>>>(x, xbp, Wih, Whh, Wib, Whb, bih, bhh, nullptr, hA, nullptr);
        lrnn_step<1,0,0><<<grid,256,0,stream>>>(x, xbp, Wih, Whh, Wib, Whb, bih, bhh, hA, hB, nullptr);
        lrnn_step<2,0,0><<<grid,256,0,stream>>>(x, xbp, Wih, Whh, Wib, Whb, bih, bhh, hB, nullptr, out);
    }
}

// Round 9
// 931.045 us; speedup vs baseline: 10.1420x; 1.5039x over previous
//
#include <hip/hip_runtime.h>
#include <hip/hip_bf16.h>
#include <stdint.h>

// LocalRNN, double-buffered merged-K MFMA version.
// A' = [x_shift | h] (K'=1024), W' = [Wih | Whh]. r,z gates accumulate merged;
// n gate split (accNi / accNh). 2-phase pipeline: stage(c+1) issued BEFORE
// compute(c), one __syncthreads per chunk (T3 minimum recipe).
// LDS: sA[2][128][64] + sW[2][192][64] bf16 = 80 KB -> 2 blocks/CU.
// Content XOR-swizzle (slot ^= row&7 within 128B rows) via pre-swizzled global
// source (G21) -> conflict-free ds_read_b128 (verified 0 conflicts round 4).

#define DDIM 512
#define LSEQ 2048
#define BATCH 32
#define MROWS (BATCH * LSEQ)   // 65536
#define MT 128                 // rows / block
#define DTG 64                 // d-cols / block
#define KC 64                  // bf16 K-chunk (128 B rows)
#define WROWS (3 * DTG)        // 192 W rows staged per chunk
#define LPAD 2                 // zero-pad rows per batch in xp
#define LROWS (LSEQ + LPAD)    // 2050

typedef short  bf16x8    __attribute__((ext_vector_type(8)));
typedef float  f32x4     __attribute__((ext_vector_type(4)));
typedef ushort ushort8_t __attribute__((ext_vector_type(8)));

__device__ __forceinline__ float sigmoid_f(float s) { return 1.0f / (1.0f + __expf(-s)); }
__device__ __forceinline__ float tanh_f(float a) {
    a = fminf(fmaxf(a, -15.0f), 15.0f);
    float e = __expf(-2.0f * a);
    return (1.0f - e) / (1.0f + e);
}
__device__ __forceinline__ ushort f2bf(float f) {
    union { __hip_bfloat16 b; ushort u; } cv; cv.b = __float2bfloat16(f); return cv.u;
}
__device__ __forceinline__ float bf2f(ushort u) {
    union { float f; uint32_t v; } cv; cv.v = ((uint32_t)u) << 16; return cv.f;
}
__device__ __forceinline__ ushort8_t pack8(float4 a, float4 b) {
    ushort8_t o = { f2bf(a.x), f2bf(a.y), f2bf(a.z), f2bf(a.w),
                    f2bf(b.x), f2bf(b.y), f2bf(b.z), f2bf(b.w) };
    return o;
}
#define GLD_LDS16(gsrc, ldst) \
    __builtin_amdgcn_global_load_lds((const __attribute__((address_space(1))) void*)(gsrc), \
                                     (__attribute__((address_space(3))) void*)(ldst), 16, 0, 0)

// ---------------- pre-pass kernels (FULL path) ----------------
__global__ __launch_bounds__(256) void conv_w(const float* __restrict__ a, const float* __restrict__ b,
                                              ushort* __restrict__ oa, ushort* __restrict__ ob) {
    size_t e = ((size_t)blockIdx.x * 256 + threadIdx.x) * 8;
    float4 p = *(const float4*)&a[e], q = *(const float4*)&a[e + 4];
    *(ushort8_t*)&oa[e] = pack8(p, q);
    p = *(const float4*)&b[e]; q = *(const float4*)&b[e + 4];
    *(ushort8_t*)&ob[e] = pack8(p, q);
}
__global__ __launch_bounds__(256) void conv_x_pad(const float* __restrict__ x, ushort* __restrict__ xp) {
    const size_t total = (size_t)MROWS * DDIM / 8;
    for (size_t u = (size_t)blockIdx.x * 256 + threadIdx.x; u < total; u += (size_t)gridDim.x * 256) {
        size_t e = u * 8;
        int m = (int)(e >> 9), col = (int)(e & 511);
        int b = m >> 11, l = m & (LSEQ - 1);
        float4 p = *(const float4*)&x[e], q = *(const float4*)&x[e + 4];
        *(ushort8_t*)&xp[((size_t)(b * LROWS + LPAD + l) << 9) + col] = pack8(p, q);
    }
}
__global__ __launch_bounds__(256) void zero_pad(ushort* __restrict__ xp) {
    int e = (blockIdx.x * 256 + threadIdx.x) * 8;     // 16 blocks cover 32*1024 elems
    int b = e >> 10, off = e & 1023;
    ushort8_t z = {0,0,0,0,0,0,0,0};
    *(ushort8_t*)&xp[(size_t)b * LROWS * DDIM + off] = z;
}

// ---------------- step kernel ----------------
// Waves: wm=wid>>1 (64-row half), wd=wid&1 (32-col half, 2 frags).
// acc: accRZ[2][4][2] + accNi[4][2] + accNh[4][2] = 32 f32x4 = 128 VGPR.
template <int T, int FULL>
__global__ __launch_bounds__(256, 2) void lrnn_step(
    const float* __restrict__ xf, const ushort* __restrict__ xp,
    const float* __restrict__ Wif, const float* __restrict__ Whf,
    const ushort* __restrict__ Wib, const ushort* __restrict__ Whb,
    const float* __restrict__ bih, const float* __restrict__ bhh,
    const ushort* __restrict__ hin, ushort* __restrict__ hout_b,
    float* __restrict__ hout_f)
{
    __shared__ ushort sA[2][MT * KC];      // 32 KB
    __shared__ ushort sW[2][WROWS * KC];   // 48 KB

    const int tid = threadIdx.x;
    const int wid = tid >> 6, lane = tid & 63;
    const int wm = wid >> 1, wd = wid & 1;
    const int lrow = lane & 15, lk = lane >> 4;
    const int d0 = blockIdx.x * DTG;
    const int m0 = blockIdx.y * MT;
    const int l0 = m0 & (LSEQ - 1);
    const int bb = m0 >> 11;
    constexpr int SHIFT = 2 - T;

    f32x4 accRZ[2][4][2], accNi[4][2], accNh[4][2];
    #pragma unroll
    for (int f = 0; f < 2; ++f) {
        int dc = d0 + wd * 32 + f * 16 + lrow;
        float brz0 = bih[dc] + bhh[dc];
        float brz1 = bih[DDIM + dc] + bhh[DDIM + dc];
        float bn_i = bih[2 * DDIM + dc];
        float bn_h = bhh[2 * DDIM + dc];   // T=0: constant bhn used in epilogue
        #pragma unroll
        for (int mi = 0; mi < 4; ++mi) {
            accRZ[0][mi][f] = { brz0, brz0, brz0, brz0 };
            accRZ[1][mi][f] = { brz1, brz1, brz1, brz1 };
            accNi[mi][f]    = { bn_i, bn_i, bn_i, bn_i };
            accNh[mi][f]    = { bn_h, bn_h, bn_h, bn_h };
        }
    }

    auto stage_x = [&](int c, int buf) {
        #pragma unroll
        for (int p = 0; p < 4; ++p) {
            int seg = p * 256 + tid, row = seg >> 3, slot = seg & 7;
            int koff = (c << 6) + ((slot ^ (row & 7)) << 3);
            if constexpr (FULL) {
                size_t srow = (size_t)(bb * LROWS + LPAD + l0 + row - SHIFT);
                GLD_LDS16(xp + (srow << 9) + koff, &sA[buf][seg * 8]);
            } else {
                int msrc = m0 + row - SHIFT; if (msrc < 0) msrc = 0;
                const float* s = xf + ((size_t)msrc << 9) + koff;
                float4 a = *(const float4*)s, b2 = *(const float4*)(s + 4);
                *(ushort8_t*)&sA[buf][seg * 8] = pack8(a, b2);
            }
        }
    };
    auto stage_h = [&](int c, int buf) {
        #pragma unroll
        for (int p = 0; p < 4; ++p) {
            int seg = p * 256 + tid, row = seg >> 3, slot = seg & 7;
            int koff = (c << 6) + ((slot ^ (row & 7)) << 3);
            GLD_LDS16(hin + ((size_t)(m0 + row) << 9) + koff, &sA[buf][seg * 8]);
        }
    };
    auto stage_w = [&](const ushort* Wb, const float* Wf, int c, int buf) {
        #pragma unroll
        for (int p = 0; p < 6; ++p) {
            int seg = p * 256 + tid, row = seg >> 3, slot = seg & 7;  // row 0..191
            int g = row >> 6, dd = row & 63;
            int koff = (c << 6) + ((slot ^ (row & 7)) << 3);
            size_t gw = ((size_t)(g * DDIM + d0 + dd) << 9) + koff;
            if constexpr (FULL) {
                GLD_LDS16(Wb + gw, &sW[buf][seg * 8]);
            } else {
                const float* s = Wf + gw;
                float4 a = *(const float4*)s, b2 = *(const float4*)(s + 4);
                *(ushort8_t*)&sW[buf][seg * 8] = pack8(a, b2);
            }
        }
    };
    auto compute = [&](int buf, f32x4 (&accN)[4][2]) {
        #pragma unroll
        for (int kk = 0; kk < 2; ++kk) {
            bf16x8 ax[4];
            #pragma unroll
            for (int mi = 0; mi < 4; ++mi) {
                int r = wm * 64 + mi * 16 + lrow;
                int sl = (kk * 4 + lk) ^ (r & 7);
                ax[mi] = *(const bf16x8*)&sA[buf][r * KC + sl * 8];
            }
            #pragma unroll
            for (int g = 0; g < 3; ++g) {
                #pragma unroll
                for (int f = 0; f < 2; ++f) {
                    int rw = g * 64 + wd * 32 + f * 16 + lrow;
                    int sl = (kk * 4 + lk) ^ (rw & 7);
                    bf16x8 bw = *(const bf16x8*)&sW[buf][rw * KC + sl * 8];
                    #pragma unroll
                    for (int mi = 0; mi < 4; ++mi) {
                        if (g < 2) accRZ[g][mi][f] = __builtin_amdgcn_mfma_f32_16x16x32_bf16(ax[mi], bw, accRZ[g][mi][f], 0, 0, 0);
                        else       accN[mi][f]    = __builtin_amdgcn_mfma_f32_16x16x32_bf16(ax[mi], bw, accN[mi][f], 0, 0, 0);
                    }
                }
            }
        }
    };

    // prologue
    stage_x(0, 0); stage_w(Wib, Wif, 0, 0);
    __syncthreads();

    // ---- x phase: chunks 0..7 (A=x_shift, W=Wih, accN=accNi) ----
    #pragma unroll
    for (int c = 0; c < 8; ++c) {
        int cb = c & 1, nb = cb ^ 1;
        if constexpr (!FULL && T < 2) {
            if (l0 == 0) {       // zero left-pad rows of current buffer
                if (tid < SHIFT * 8) {
                    ushort8_t z = {0,0,0,0,0,0,0,0};
                    *(ushort8_t*)&sA[cb][tid * 8] = z;
                }
                __syncthreads();
            }
        }
        if (c < 7)          { stage_x(c + 1, nb); stage_w(Wib, Wif, c + 1, nb); }
        else if (T > 0)     { stage_h(0, nb);     stage_w(Whb, Whf, 0, nb); }
        compute(cb, accNi);
        __syncthreads();
    }
    // ---- h phase: chunks 0..7 (A=h, W=Whh, accN=accNh) ----
    if constexpr (T > 0) {
        #pragma unroll
        for (int c = 0; c < 8; ++c) {
            int cb = c & 1, nb = cb ^ 1;
            if (c < 7) { stage_h(c + 1, nb); stage_w(Whb, Whf, c + 1, nb); }
            compute(cb, accNh);
            __syncthreads();
        }
    }

    // ---- epilogue (C/D: col=lane&15, row=lk*4+j) ----
    #pragma unroll
    for (int mi = 0; mi < 4; ++mi)
    #pragma unroll
    for (int f = 0; f < 2; ++f)
    #pragma unroll
    for (int j = 0; j < 4; ++j) {
        int m = m0 + wm * 64 + mi * 16 + lk * 4 + j;
        int dc = d0 + wd * 32 + f * 16 + lrow;
        size_t off = ((size_t)m << 9) + dc;
        float r = sigmoid_f(accRZ[0][mi][f][j]);
        float z = sigmoid_f(accRZ[1][mi][f][j]);
        float n = tanh_f(accNi[mi][f][j] + r * accNh[mi][f][j]);
        float h;
        if constexpr (T > 0) h = (1.0f - z) * n + z * bf2f(hin[off]);
        else                 h = (1.0f - z) * n;
        if constexpr (T == 2) hout_f[off] = h;
        else                  hout_b[off] = f2bf(h);
    }
}

extern "C" void kernel_launch(void* const* d_in, const int* in_sizes, int n_in,
                              void* d_out, int out_size, void* d_ws, size_t ws_size,
                              hipStream_t stream) {
    const float* x   = (const float*)d_in[0];
    const float* Wih = (const float*)d_in[1];
    const float* Whh = (const float*)d_in[2];
    const float* bih = (const float*)d_in[3];
    const float* bhh = (const float*)d_in[4];
    float* out = (float*)d_out;

    const size_t HELEMS  = (size_t)MROWS * DDIM;        // 33,554,432
    const size_t WELEMS  = (size_t)3 * DDIM * DDIM;     // 786,432
    const size_t XPELEMS = (size_t)BATCH * LROWS * DDIM;// 33,587,200
    ushort* hA  = (ushort*)d_ws;
    ushort* hB  = hA + HELEMS;
    ushort* Wib = hB + HELEMS;
    ushort* Whb = Wib + WELEMS;
    ushort* xpp = Whb + WELEMS;
    const size_t NEED_FULL = (2 * HELEMS + 2 * WELEMS + XPELEMS) * 2;  // ~204.5 MB
    const bool full = ws_size >= NEED_FULL;

    dim3 grid(DDIM / DTG, MROWS / MT);   // (8, 512)
    if (full) {
        conv_w<<<(int)(WELEMS / 8 / 256), 256, 0, stream>>>(Wih, Whh, Wib, Whb);
        conv_x_pad<<<2048, 256, 0, stream>>>(x, xpp);
        zero_pad<<<16, 256, 0, stream>>>(xpp);
        lrnn_step<0,1><<<grid,256,0,stream>>>(x, xpp, Wih, Whh, Wib, Whb, bih, bhh, nullptr, hA, nullptr);
        lrnn_step<1,1><<<grid,256,0,stream>>>(x, xpp, Wih, Whh, Wib, Whb, bih, bhh, hA, hB, nullptr);
        lrnn_step<2,1><<<grid,256,0,stream>>>(x, xpp, Wih, Whh, Wib, Whb, bih, bhh, hB, nullptr, out);
    } else {
        lrnn_step<0,0><<<grid,256,0,stream>>>(x, xpp, Wih, Whh, Wib, Whb, bih, bhh, nullptr, hA, nullptr);
        lrnn_step<1,0><<<grid,256,0,stream>>>(x, xpp, Wih, Whh, Wib, Whb, bih, bhh, hA, hB, nullptr);
        lrnn_step<2,0><<<grid,256,0,stream>>>(x, xpp, Wih, Whh, Wib, Whb, bih, bhh, hB, nullptr, out);
    }
}

// Round 10
// 869.792 us; speedup vs baseline: 10.8562x; 1.0704x over previous
//
#include <hip/hip_runtime.h>
#include <hip/hip_bf16.h>
#include <stdint.h>

// LocalRNN, double-buffered merged-K MFMA version + XCD-aware block swizzle.
// A' = [x_shift | h] (K'=1024), W' = [Wih | Whh]. r,z gates accumulate merged;
// n gate split (accNi / accNh). 2-phase pipeline: stage(c+1) issued BEFORE
// compute(c), one __syncthreads per chunk.
// XCD swizzle (T1): bid = by*8+bx (dispatch order); xcd = bid&7 owns a
// contiguous 64-m-tile range; the 8 d-blocks of each m-tile are consecutive
// on the SAME XCD -> x/h tiles hit L2 7/8 times, W (3 MB) stays L2-resident.
// LDS: sA[2][128][64] + sW[2][192][64] bf16 = 80 KB -> 2 blocks/CU.
// Content XOR-swizzle (slot ^= row&7) via pre-swizzled global source (G21)
// -> conflict-free ds_read_b128 (verified 0 conflicts rounds 4/9).

#define DDIM 512
#define LSEQ 2048
#define BATCH 32
#define MROWS (BATCH * LSEQ)   // 65536
#define MT 128                 // rows / block
#define DTG 64                 // d-cols / block
#define KC 64                  // bf16 K-chunk (128 B rows)
#define WROWS (3 * DTG)        // 192 W rows staged per chunk
#define LPAD 2                 // zero-pad rows per batch in xp
#define LROWS (LSEQ + LPAD)    // 2050

typedef short  bf16x8    __attribute__((ext_vector_type(8)));
typedef float  f32x4     __attribute__((ext_vector_type(4)));
typedef ushort ushort8_t __attribute__((ext_vector_type(8)));

__device__ __forceinline__ float sigmoid_f(float s) { return 1.0f / (1.0f + __expf(-s)); }
__device__ __forceinline__ float tanh_f(float a) {
    a = fminf(fmaxf(a, -15.0f), 15.0f);
    float e = __expf(-2.0f * a);
    return (1.0f - e) / (1.0f + e);
}
__device__ __forceinline__ ushort f2bf(float f) {
    union { __hip_bfloat16 b; ushort u; } cv; cv.b = __float2bfloat16(f); return cv.u;
}
__device__ __forceinline__ float bf2f(ushort u) {
    union { float f; uint32_t v; } cv; cv.v = ((uint32_t)u) << 16; return cv.f;
}
__device__ __forceinline__ ushort8_t pack8(float4 a, float4 b) {
    ushort8_t o = { f2bf(a.x), f2bf(a.y), f2bf(a.z), f2bf(a.w),
                    f2bf(b.x), f2bf(b.y), f2bf(b.z), f2bf(b.w) };
    return o;
}
#define GLD_LDS16(gsrc, ldst) \
    __builtin_amdgcn_global_load_lds((const __attribute__((address_space(1))) void*)(gsrc), \
                                     (__attribute__((address_space(3))) void*)(ldst), 16, 0, 0)

// ---------------- pre-pass kernels (FULL path) ----------------
__global__ __launch_bounds__(256) void conv_w(const float* __restrict__ a, const float* __restrict__ b,
                                              ushort* __restrict__ oa, ushort* __restrict__ ob) {
    size_t e = ((size_t)blockIdx.x * 256 + threadIdx.x) * 8;
    float4 p = *(const float4*)&a[e], q = *(const float4*)&a[e + 4];
    *(ushort8_t*)&oa[e] = pack8(p, q);
    p = *(const float4*)&b[e]; q = *(const float4*)&b[e + 4];
    *(ushort8_t*)&ob[e] = pack8(p, q);
}
__global__ __launch_bounds__(256) void conv_x_pad(const float* __restrict__ x, ushort* __restrict__ xp) {
    const size_t total = (size_t)MROWS * DDIM / 8;
    for (size_t u = (size_t)blockIdx.x * 256 + threadIdx.x; u < total; u += (size_t)gridDim.x * 256) {
        size_t e = u * 8;
        int m = (int)(e >> 9), col = (int)(e & 511);
        int b = m >> 11, l = m & (LSEQ - 1);
        float4 p = *(const float4*)&x[e], q = *(const float4*)&x[e + 4];
        *(ushort8_t*)&xp[((size_t)(b * LROWS + LPAD + l) << 9) + col] = pack8(p, q);
    }
}
__global__ __launch_bounds__(256) void zero_pad(ushort* __restrict__ xp) {
    int e = (blockIdx.x * 256 + threadIdx.x) * 8;     // 16 blocks cover 32*1024 elems
    int b = e >> 10, off = e & 1023;
    ushort8_t z = {0,0,0,0,0,0,0,0};
    *(ushort8_t*)&xp[(size_t)b * LROWS * DDIM + off] = z;
}

// ---------------- step kernel ----------------
// Waves: wm=wid>>1 (64-row half), wd=wid&1 (32-col half, 2 frags).
// acc: accRZ[2][4][2] + accNi[4][2] + accNh[4][2] = 32 f32x4 = 128 VGPR.
template <int T, int FULL>
__global__ __launch_bounds__(256, 2) void lrnn_step(
    const float* __restrict__ xf, const ushort* __restrict__ xp,
    const float* __restrict__ Wif, const float* __restrict__ Whf,
    const ushort* __restrict__ Wib, const ushort* __restrict__ Whb,
    const float* __restrict__ bih, const float* __restrict__ bhh,
    const ushort* __restrict__ hin, ushort* __restrict__ hout_b,
    float* __restrict__ hout_f)
{
    __shared__ ushort sA[2][MT * KC];      // 32 KB
    __shared__ ushort sW[2][WROWS * KC];   // 48 KB

    const int tid = threadIdx.x;
    const int wid = tid >> 6, lane = tid & 63;
    const int wm = wid >> 1, wd = wid & 1;
    const int lrow = lane & 15, lk = lane >> 4;
    // ---- XCD-aware swizzle: bijective remap of 4096 block ids ----
    // bid dispatch-linear (x fastest). xcd = bid&7 (round-robin placement).
    // XCD k -> m-tiles [k*64, (k+1)*64), d cycling fastest within the XCD.
    const int bid = blockIdx.y * 8 + blockIdx.x;
    const int xcd = bid & 7;
    const int idx = bid >> 3;               // 0..511 (per-XCD sequence)
    const int d0  = (idx & 7) * DTG;
    const int m0  = (xcd * 64 + (idx >> 3)) * MT;
    const int l0 = m0 & (LSEQ - 1);
    const int bb = m0 >> 11;
    constexpr int SHIFT = 2 - T;

    f32x4 accRZ[2][4][2], accNi[4][2], accNh[4][2];
    #pragma unroll
    for (int f = 0; f < 2; ++f) {
        int dc = d0 + wd * 32 + f * 16 + lrow;
        float brz0 = bih[dc] + bhh[dc];
        float brz1 = bih[DDIM + dc] + bhh[DDIM + dc];
        float bn_i = bih[2 * DDIM + dc];
        float bn_h = bhh[2 * DDIM + dc];   // T=0: constant bhn used in epilogue
        #pragma unroll
        for (int mi = 0; mi < 4; ++mi) {
            accRZ[0][mi][f] = { brz0, brz0, brz0, brz0 };
            accRZ[1][mi][f] = { brz1, brz1, brz1, brz1 };
            accNi[mi][f]    = { bn_i, bn_i, bn_i, bn_i };
            accNh[mi][f]    = { bn_h, bn_h, bn_h, bn_h };
        }
    }

    auto stage_x = [&](int c, int buf) {
        #pragma unroll
        for (int p = 0; p < 4; ++p) {
            int seg = p * 256 + tid, row = seg >> 3, slot = seg & 7;
            int koff = (c << 6) + ((slot ^ (row & 7)) << 3);
            if constexpr (FULL) {
                size_t srow = (size_t)(bb * LROWS + LPAD + l0 + row - SHIFT);
                GLD_LDS16(xp + (srow << 9) + koff, &sA[buf][seg * 8]);
            } else {
                int msrc = m0 + row - SHIFT; if (msrc < 0) msrc = 0;
                const float* s = xf + ((size_t)msrc << 9) + koff;
                float4 a = *(const float4*)s, b2 = *(const float4*)(s + 4);
                *(ushort8_t*)&sA[buf][seg * 8] = pack8(a, b2);
            }
        }
    };
    auto stage_h = [&](int c, int buf) {
        #pragma unroll
        for (int p = 0; p < 4; ++p) {
            int seg = p * 256 + tid, row = seg >> 3, slot = seg & 7;
            int koff = (c << 6) + ((slot ^ (row & 7)) << 3);
            GLD_LDS16(hin + ((size_t)(m0 + row) << 9) + koff, &sA[buf][seg * 8]);
        }
    };
    auto stage_w = [&](const ushort* Wb, const float* Wf, int c, int buf) {
        #pragma unroll
        for (int p = 0; p < 6; ++p) {
            int seg = p * 256 + tid, row = seg >> 3, slot = seg & 7;  // row 0..191
            int g = row >> 6, dd = row & 63;
            int koff = (c << 6) + ((slot ^ (row & 7)) << 3);
            size_t gw = ((size_t)(g * DDIM + d0 + dd) << 9) + koff;
            if constexpr (FULL) {
                GLD_LDS16(Wb + gw, &sW[buf][seg * 8]);
            } else {
                const float* s = Wf + gw;
                float4 a = *(const float4*)s, b2 = *(const float4*)(s + 4);
                *(ushort8_t*)&sW[buf][seg * 8] = pack8(a, b2);
            }
        }
    };
    auto compute = [&](int buf, f32x4 (&accN)[4][2]) {
        #pragma unroll
        for (int kk = 0; kk < 2; ++kk) {
            bf16x8 ax[4];
            #pragma unroll
            for (int mi = 0; mi < 4; ++mi) {
                int r = wm * 64 + mi * 16 + lrow;
                int sl = (kk * 4 + lk) ^ (r & 7);
                ax[mi] = *(const bf16x8*)&sA[buf][r * KC + sl * 8];
            }
            #pragma unroll
            for (int g = 0; g < 3; ++g) {
                #pragma unroll
                for (int f = 0; f < 2; ++f) {
                    int rw = g * 64 + wd * 32 + f * 16 + lrow;
                    int sl = (kk * 4 + lk) ^ (rw & 7);
                    bf16x8 bw = *(const bf16x8*)&sW[buf][rw * KC + sl * 8];
                    #pragma unroll
                    for (int mi = 0; mi < 4; ++mi) {
                        if (g < 2) accRZ[g][mi][f] = __builtin_amdgcn_mfma_f32_16x16x32_bf16(ax[mi], bw, accRZ[g][mi][f], 0, 0, 0);
                        else       accN[mi][f]    = __builtin_amdgcn_mfma_f32_16x16x32_bf16(ax[mi], bw, accN[mi][f], 0, 0, 0);
                    }
                }
            }
        }
    };

    // prologue
    stage_x(0, 0); stage_w(Wib, Wif, 0, 0);
    __syncthreads();

    // ---- x phase: chunks 0..7 (A=x_shift, W=Wih, accN=accNi) ----
    #pragma unroll
    for (int c = 0; c < 8; ++c) {
        int cb = c & 1, nb = cb ^ 1;
        if constexpr (!FULL && T < 2) {
            if (l0 == 0) {       // zero left-pad rows of current buffer
                if (tid < SHIFT * 8) {
                    ushort8_t z = {0,0,0,0,0,0,0,0};
                    *(ushort8_t*)&sA[cb][tid * 8] = z;
                }
                __syncthreads();
            }
        }
        if (c < 7)          { stage_x(c + 1, nb); stage_w(Wib, Wif, c + 1, nb); }
        else if (T > 0)     { stage_h(0, nb);     stage_w(Whb, Whf, 0, nb); }
        compute(cb, accNi);
        __syncthreads();
    }
    // ---- h phase: chunks 0..7 (A=h, W=Whh, accN=accNh) ----
    if constexpr (T > 0) {
        #pragma unroll
        for (int c = 0; c < 8; ++c) {
            int cb = c & 1, nb = cb ^ 1;
            if (c < 7) { stage_h(c + 1, nb); stage_w(Whb, Whf, c + 1, nb); }
            compute(cb, accNh);
            __syncthreads();
        }
    }

    // ---- epilogue (C/D: col=lane&15, row=lk*4+j) ----
    #pragma unroll
    for (int mi = 0; mi < 4; ++mi)
    #pragma unroll
    for (int f = 0; f < 2; ++f)
    #pragma unroll
    for (int j = 0; j < 4; ++j) {
        int m = m0 + wm * 64 + mi * 16 + lk * 4 + j;
        int dc = d0 + wd * 32 + f * 16 + lrow;
        size_t off = ((size_t)m << 9) + dc;
        float r = sigmoid_f(accRZ[0][mi][f][j]);
        float z = sigmoid_f(accRZ[1][mi][f][j]);
        float n = tanh_f(accNi[mi][f][j] + r * accNh[mi][f][j]);
        float h;
        if constexpr (T > 0) h = (1.0f - z) * n + z * bf2f(hin[off]);
        else                 h = (1.0f - z) * n;
        if constexpr (T == 2) hout_f[off] = h;
        else                  hout_b[off] = f2bf(h);
    }
}

extern "C" void kernel_launch(void* const* d_in, const int* in_sizes, int n_in,
                              void* d_out, int out_size, void* d_ws, size_t ws_size,
                              hipStream_t stream) {
    const float* x   = (const float*)d_in[0];
    const float* Wih = (const float*)d_in[1];
    const float* Whh = (const float*)d_in[2];
    const float* bih = (const float*)d_in[3];
    const float* bhh = (const float*)d_in[4];
    float* out = (float*)d_out;

    const size_t HELEMS  = (size_t)MROWS * DDIM;        // 33,554,432
    const size_t WELEMS  = (size_t)3 * DDIM * DDIM;     // 786,432
    const size_t XPELEMS = (size_t)BATCH * LROWS * DDIM;// 33,587,200
    ushort* hA  = (ushort*)d_ws;
    ushort* hB  = hA + HELEMS;
    ushort* Wib = hB + HELEMS;
    ushort* Whb = Wib + WELEMS;
    ushort* xpp = Whb + WELEMS;
    const size_t NEED_FULL = (2 * HELEMS + 2 * WELEMS + XPELEMS) * 2;  // ~204.5 MB
    const bool full = ws_size >= NEED_FULL;

    dim3 grid(DDIM / DTG, MROWS / MT);   // (8, 512)
    if (full) {
        conv_w<<<(int)(WELEMS / 8 / 256), 256, 0, stream>>>(Wih, Whh, Wib, Whb);
        conv_x_pad<<<2048, 256, 0, stream>>>(x, xpp);
        zero_pad<<<16, 256, 0, stream>>>(xpp);
        lrnn_step<0,1><<<grid,256,0,stream>>>(x, xpp, Wih, Whh, Wib, Whb, bih, bhh, nullptr, hA, nullptr);
        lrnn_step<1,1><<<grid,256,0,stream>>>(x, xpp, Wih, Whh, Wib, Whb, bih, bhh, hA, hB, nullptr);
        lrnn_step<2,1><<<grid,256,0,stream>>>(x, xpp, Wih, Whh, Wib, Whb, bih, bhh, hB, nullptr, out);
    } else {
        lrnn_step<0,0><<<grid,256,0,stream>>>(x, xpp, Wih, Whh, Wib, Whb, bih, bhh, nullptr, hA, nullptr);
        lrnn_step<1,0><<<grid,256,0,stream>>>(x, xpp, Wih, Whh, Wib, Whb, bih, bhh, hA, hB, nullptr);
        lrnn_step<2,0><<<grid,256,0,stream>>>(x, xpp, Wih, Whh, Wib, Whb, bih, bhh, hB, nullptr, out);
    }
}

// Round 11
// 846.703 us; speedup vs baseline: 11.1522x; 1.0273x over previous
//
#include <hip/hip_runtime.h>
#include <hip/hip_bf16.h>
#include <stdint.h>

// LocalRNN, merged-K MFMA + XCD swizzle + T4 counted-vmcnt pipeline.
// A' = [x_shift | h] (K'=1024), W' = [Wih | Whh]; r,z merged accum, n split.
// Chunk loop (FULL): barrier; stage(c+1); s_waitcnt vmcnt(10); barrier;
// compute(c). The counted wait only drains stage(c) (issued one full chunk
// earlier); stage(c+1)'s 10 global_load_lds stay in flight across the
// barrier and complete under compute(c) (T4, m218). Never vmcnt(0) in-loop.
// XCD swizzle (T1): xcd=bid&7 owns contiguous m-range, d fastest within XCD
// (round 10: FETCH 594->283 MB). Content XOR-swizzle -> 0 bank conflicts.
// LDS: sA[2][128][64] + sW[2][192][64] bf16 = 80 KB -> 2 blocks/CU.

#define DDIM 512
#define LSEQ 2048
#define BATCH 32
#define MROWS (BATCH * LSEQ)   // 65536
#define MT 128                 // rows / block
#define DTG 64                 // d-cols / block
#define KC 64                  // bf16 K-chunk (128 B rows)
#define WROWS (3 * DTG)        // 192 W rows staged per chunk
#define LPAD 2                 // zero-pad rows per batch in xp
#define LROWS (LSEQ + LPAD)    // 2050

typedef short  bf16x8    __attribute__((ext_vector_type(8)));
typedef float  f32x4     __attribute__((ext_vector_type(4)));
typedef ushort ushort8_t __attribute__((ext_vector_type(8)));

__device__ __forceinline__ float sigmoid_f(float s) { return 1.0f / (1.0f + __expf(-s)); }
__device__ __forceinline__ float tanh_f(float a) {
    a = fminf(fmaxf(a, -15.0f), 15.0f);
    float e = __expf(-2.0f * a);
    return (1.0f - e) / (1.0f + e);
}
__device__ __forceinline__ ushort f2bf(float f) {
    union { __hip_bfloat16 b; ushort u; } cv; cv.b = __float2bfloat16(f); return cv.u;
}
__device__ __forceinline__ float bf2f(ushort u) {
    union { float f; uint32_t v; } cv; cv.v = ((uint32_t)u) << 16; return cv.f;
}
__device__ __forceinline__ ushort8_t pack8(float4 a, float4 b) {
    ushort8_t o = { f2bf(a.x), f2bf(a.y), f2bf(a.z), f2bf(a.w),
                    f2bf(b.x), f2bf(b.y), f2bf(b.z), f2bf(b.w) };
    return o;
}
#define GLD_LDS16(gsrc, ldst) \
    __builtin_amdgcn_global_load_lds((const __attribute__((address_space(1))) void*)(gsrc), \
                                     (__attribute__((address_space(3))) void*)(ldst), 16, 0, 0)

// ---------------- pre-pass kernels (FULL path) ----------------
__global__ __launch_bounds__(256) void conv_w(const float* __restrict__ a, const float* __restrict__ b,
                                              ushort* __restrict__ oa, ushort* __restrict__ ob) {
    size_t e = ((size_t)blockIdx.x * 256 + threadIdx.x) * 8;
    float4 p = *(const float4*)&a[e], q = *(const float4*)&a[e + 4];
    *(ushort8_t*)&oa[e] = pack8(p, q);
    p = *(const float4*)&b[e]; q = *(const float4*)&b[e + 4];
    *(ushort8_t*)&ob[e] = pack8(p, q);
}
__global__ __launch_bounds__(256) void conv_x_pad(const float* __restrict__ x, ushort* __restrict__ xp) {
    const size_t total = (size_t)MROWS * DDIM / 8;
    for (size_t u = (size_t)blockIdx.x * 256 + threadIdx.x; u < total; u += (size_t)gridDim.x * 256) {
        size_t e = u * 8;
        int m = (int)(e >> 9), col = (int)(e & 511);
        int b = m >> 11, l = m & (LSEQ - 1);
        float4 p = *(const float4*)&x[e], q = *(const float4*)&x[e + 4];
        *(ushort8_t*)&xp[((size_t)(b * LROWS + LPAD + l) << 9) + col] = pack8(p, q);
    }
}
__global__ __launch_bounds__(256) void zero_pad(ushort* __restrict__ xp) {
    int e = (blockIdx.x * 256 + threadIdx.x) * 8;     // 16 blocks cover 32*1024 elems
    int b = e >> 10, off = e & 1023;
    ushort8_t z = {0,0,0,0,0,0,0,0};
    *(ushort8_t*)&xp[(size_t)b * LROWS * DDIM + off] = z;
}

// ---------------- step kernel ----------------
// Waves: wm=wid>>1 (64-row half), wd=wid&1 (32-col half, 2 frags).
// acc: accRZ[2][4][2] + accNi[4][2] + accNh[4][2] = 32 f32x4 = 128 VGPR.
template <int T, int FULL>
__global__ __launch_bounds__(256, 2) void lrnn_step(
    const float* __restrict__ xf, const ushort* __restrict__ xp,
    const float* __restrict__ Wif, const float* __restrict__ Whf,
    const ushort* __restrict__ Wib, const ushort* __restrict__ Whb,
    const float* __restrict__ bih, const float* __restrict__ bhh,
    const ushort* __restrict__ hin, ushort* __restrict__ hout_b,
    float* __restrict__ hout_f)
{
    __shared__ ushort sA[2][MT * KC];      // 32 KB
    __shared__ ushort sW[2][WROWS * KC];   // 48 KB

    const int tid = threadIdx.x;
    const int wid = tid >> 6, lane = tid & 63;
    const int wm = wid >> 1, wd = wid & 1;
    const int lrow = lane & 15, lk = lane >> 4;
    // ---- XCD-aware swizzle (T1): xcd = bid&7 owns m-tiles [xcd*64,(xcd+1)*64),
    // d cycles fastest within the XCD ----
    const int bid = blockIdx.y * 8 + blockIdx.x;
    const int xcd = bid & 7;
    const int idx = bid >> 3;               // 0..511
    const int d0  = (idx & 7) * DTG;
    const int m0  = (xcd * 64 + (idx >> 3)) * MT;
    const int l0 = m0 & (LSEQ - 1);
    const int bb = m0 >> 11;
    constexpr int SHIFT = 2 - T;
    constexpr int NCH = (T > 0) ? 16 : 8;   // unified chunk count

    f32x4 accRZ[2][4][2], accNi[4][2], accNh[4][2];
    #pragma unroll
    for (int f = 0; f < 2; ++f) {
        int dc = d0 + wd * 32 + f * 16 + lrow;
        float brz0 = bih[dc] + bhh[dc];
        float brz1 = bih[DDIM + dc] + bhh[DDIM + dc];
        float bn_i = bih[2 * DDIM + dc];
        float bn_h = bhh[2 * DDIM + dc];   // T=0: constant bhn used in epilogue
        #pragma unroll
        for (int mi = 0; mi < 4; ++mi) {
            accRZ[0][mi][f] = { brz0, brz0, brz0, brz0 };
            accRZ[1][mi][f] = { brz1, brz1, brz1, brz1 };
            accNi[mi][f]    = { bn_i, bn_i, bn_i, bn_i };
            accNh[mi][f]    = { bn_h, bn_h, bn_h, bn_h };
        }
    }

    auto stage_x = [&](int c, int buf) {
        #pragma unroll
        for (int p = 0; p < 4; ++p) {
            int seg = p * 256 + tid, row = seg >> 3, slot = seg & 7;
            int koff = (c << 6) + ((slot ^ (row & 7)) << 3);
            if constexpr (FULL) {
                size_t srow = (size_t)(bb * LROWS + LPAD + l0 + row - SHIFT);
                GLD_LDS16(xp + (srow << 9) + koff, &sA[buf][seg * 8]);
            } else {
                int msrc = m0 + row - SHIFT; if (msrc < 0) msrc = 0;
                const float* s = xf + ((size_t)msrc << 9) + koff;
                float4 a = *(const float4*)s, b2 = *(const float4*)(s + 4);
                *(ushort8_t*)&sA[buf][seg * 8] = pack8(a, b2);
            }
        }
    };
    auto stage_h = [&](int c, int buf) {
        #pragma unroll
        for (int p = 0; p < 4; ++p) {
            int seg = p * 256 + tid, row = seg >> 3, slot = seg & 7;
            int koff = (c << 6) + ((slot ^ (row & 7)) << 3);
            GLD_LDS16(hin + ((size_t)(m0 + row) << 9) + koff, &sA[buf][seg * 8]);
        }
    };
    auto stage_w = [&](const ushort* Wb, const float* Wf, int c, int buf) {
        #pragma unroll
        for (int p = 0; p < 6; ++p) {
            int seg = p * 256 + tid, row = seg >> 3, slot = seg & 7;  // row 0..191
            int g = row >> 6, dd = row & 63;
            int koff = (c << 6) + ((slot ^ (row & 7)) << 3);
            size_t gw = ((size_t)(g * DDIM + d0 + dd) << 9) + koff;
            if constexpr (FULL) {
                GLD_LDS16(Wb + gw, &sW[buf][seg * 8]);
            } else {
                const float* s = Wf + gw;
                float4 a = *(const float4*)s, b2 = *(const float4*)(s + 4);
                *(ushort8_t*)&sW[buf][seg * 8] = pack8(a, b2);
            }
        }
    };
    auto compute = [&](int buf, f32x4 (&accN)[4][2]) {
        #pragma unroll
        for (int kk = 0; kk < 2; ++kk) {
            bf16x8 ax[4];
            #pragma unroll
            for (int mi = 0; mi < 4; ++mi) {
                int r = wm * 64 + mi * 16 + lrow;
                int sl = (kk * 4 + lk) ^ (r & 7);
                ax[mi] = *(const bf16x8*)&sA[buf][r * KC + sl * 8];
            }
            #pragma unroll
            for (int g = 0; g < 3; ++g) {
                #pragma unroll
                for (int f = 0; f < 2; ++f) {
                    int rw = g * 64 + wd * 32 + f * 16 + lrow;
                    int sl = (kk * 4 + lk) ^ (rw & 7);
                    bf16x8 bw = *(const bf16x8*)&sW[buf][rw * KC + sl * 8];
                    #pragma unroll
                    for (int mi = 0; mi < 4; ++mi) {
                        if (g < 2) accRZ[g][mi][f] = __builtin_amdgcn_mfma_f32_16x16x32_bf16(ax[mi], bw, accRZ[g][mi][f], 0, 0, 0);
                        else       accN[mi][f]    = __builtin_amdgcn_mfma_f32_16x16x32_bf16(ax[mi], bw, accN[mi][f], 0, 0, 0);
                    }
                }
            }
        }
    };
    auto stage_any = [&](int c, int buf) {   // c in [0,NCH)
        if (c < 8) { stage_x(c, buf);     stage_w(Wib, Wif, c, buf); }
        else       { stage_h(c - 8, buf); stage_w(Whb, Whf, c - 8, buf); }
    };

    if constexpr (FULL) {
        // ---- T4 counted-vmcnt pipeline: 10 gld_lds per wave per chunk ----
        stage_any(0, 0);   // prologue issue (no wait; c=0's vmcnt(10) covers it)
        #pragma unroll
        for (int c = 0; c < NCH; ++c) {
            const int cb = c & 1, nb = cb ^ 1;
            __builtin_amdgcn_s_barrier();          // prev compute done reading nb
            if (c + 1 < NCH) {
                stage_any(c + 1, nb);              // issue next (stays in flight)
                asm volatile("s_waitcnt vmcnt(10)" ::: "memory");  // stage(c) landed
            } else {
                asm volatile("s_waitcnt vmcnt(0)" ::: "memory");
            }
            __builtin_amdgcn_s_barrier();          // all waves' stage(c) visible
            if (c < 8) compute(cb, accNi);
            else       compute(cb, accNh);
        }
    } else {
        // ---- fallback: proven round-9 drain-0 structure ----
        stage_x(0, 0); stage_w(Wib, Wif, 0, 0);
        __syncthreads();
        #pragma unroll
        for (int c = 0; c < 8; ++c) {
            int cb = c & 1, nb = cb ^ 1;
            if constexpr (T < 2) {
                if (l0 == 0) {
                    if (tid < SHIFT * 8) {
                        ushort8_t z = {0,0,0,0,0,0,0,0};
                        *(ushort8_t*)&sA[cb][tid * 8] = z;
                    }
                    __syncthreads();
                }
            }
            if (c < 7)      { stage_x(c + 1, nb); stage_w(Wib, Wif, c + 1, nb); }
            else if (T > 0) { stage_h(0, nb);     stage_w(Whb, Whf, 0, nb); }
            compute(cb, accNi);
            __syncthreads();
        }
        if constexpr (T > 0) {
            #pragma unroll
            for (int c = 0; c < 8; ++c) {
                int cb = c & 1, nb = cb ^ 1;
                if (c < 7) { stage_h(c + 1, nb); stage_w(Whb, Whf, c + 1, nb); }
                compute(cb, accNh);
                __syncthreads();
            }
        }
    }

    // ---- epilogue (C/D: col=lane&15, row=lk*4+j) ----
    #pragma unroll
    for (int mi = 0; mi < 4; ++mi)
    #pragma unroll
    for (int f = 0; f < 2; ++f)
    #pragma unroll
    for (int j = 0; j < 4; ++j) {
        int m = m0 + wm * 64 + mi * 16 + lk * 4 + j;
        int dc = d0 + wd * 32 + f * 16 + lrow;
        size_t off = ((size_t)m << 9) + dc;
        float r = sigmoid_f(accRZ[0][mi][f][j]);
        float z = sigmoid_f(accRZ[1][mi][f][j]);
        float n = tanh_f(accNi[mi][f][j] + r * accNh[mi][f][j]);
        float h;
        if constexpr (T > 0) h = (1.0f - z) * n + z * bf2f(hin[off]);
        else                 h = (1.0f - z) * n;
        if constexpr (T == 2) hout_f[off] = h;
        else                  hout_b[off] = f2bf(h);
    }
}

extern "C" void kernel_launch(void* const* d_in, const int* in_sizes, int n_in,
                              void* d_out, int out_size, void* d_ws, size_t ws_size,
                              hipStream_t stream) {
    const float* x   = (const float*)d_in[0];
    const float* Wih = (const float*)d_in[1];
    const float* Whh = (const float*)d_in[2];
    const float* bih = (const float*)d_in[3];
    const float* bhh = (const float*)d_in[4];
    float* out = (float*)d_out;

    const size_t HELEMS  = (size_t)MROWS * DDIM;        // 33,554,432
    const size_t WELEMS  = (size_t)3 * DDIM * DDIM;     // 786,432
    const size_t XPELEMS = (size_t)BATCH * LROWS * DDIM;// 33,587,200
    ushort* hA  = (ushort*)d_ws;
    ushort* hB  = hA + HELEMS;
    ushort* Wib = hB + HELEMS;
    ushort* Whb = Wib + WELEMS;
    ushort* xpp = Whb + WELEMS;
    const size_t NEED_FULL = (2 * HELEMS + 2 * WELEMS + XPELEMS) * 2;  // ~204.5 MB
    const bool full = ws_size >= NEED_FULL;

    dim3 grid(DDIM / DTG, MROWS / MT);   // (8, 512)
    if (full) {
        conv_w<<<(int)(WELEMS / 8 / 256), 256, 0, stream>>>(Wih, Whh, Wib, Whb);
        conv_x_pad<<<2048, 256, 0, stream>>>(x, xpp);
        zero_pad<<<16, 256, 0, stream>>>(xpp);
        lrnn_step<0,1><<<grid,256,0,stream>>>(x, xpp, Wih, Whh, Wib, Whb, bih, bhh, nullptr, hA, nullptr);
        lrnn_step<1,1><<<grid,256,0,stream>>>(x, xpp, Wih, Whh, Wib, Whb, bih, bhh, hA, hB, nullptr);
        lrnn_step<2,1><<<grid,256,0,stream>>>(x, xpp, Wih, Whh, Wib, Whb, bih, bhh, hB, nullptr, out);
    } else {
        lrnn_step<0,0><<<grid,256,0,stream>>>(x, xpp, Wih, Whh, Wib, Whb, bih, bhh, nullptr, hA, nullptr);
        lrnn_step<1,0><<<grid,256,0,stream>>>(x, xpp, Wih, Whh, Wib, Whb, bih, bhh, hA, hB, nullptr);
        lrnn_step<2,0><<<grid,256,0,stream>>>(x, xpp, Wih, Whh, Wib, Whb, bih, bhh, hB, nullptr, out);
    }
}